// Round 3
// baseline (755.334 us; speedup 1.0000x reference)
//
#include <hip/hip_runtime.h>
#include <stdint.h>

// ---- problem constants ----
#define BB   8
#define LL   8192
#define HH   8
#define DH   64
#define DIMM 512
#define KS_  13
// dilation = 2, ns = 6

typedef unsigned short ushort_t;
typedef __attribute__((ext_vector_type(8))) short bf16x8;   // 8 x bf16 (4 VGPRs)
typedef __attribute__((ext_vector_type(4))) float f32x4;

#define AS1 __attribute__((address_space(1)))
#define AS3 __attribute__((address_space(3)))

__device__ __forceinline__ unsigned short f2bf(float f) {
    unsigned u = __float_as_uint(f);
    u += 0x7fffu + ((u >> 16) & 1u);       // round-to-nearest-even
    return (unsigned short)(u >> 16);
}
__device__ __forceinline__ void unpack8(uint4 u, float* f) {
    f[0] = __uint_as_float(u.x << 16); f[1] = __uint_as_float(u.x & 0xffff0000u);
    f[2] = __uint_as_float(u.y << 16); f[3] = __uint_as_float(u.y & 0xffff0000u);
    f[4] = __uint_as_float(u.z << 16); f[5] = __uint_as_float(u.z & 0xffff0000u);
    f[6] = __uint_as_float(u.w << 16); f[7] = __uint_as_float(u.w & 0xffff0000u);
}
__device__ __forceinline__ uint4 pack8(const float4 a, const float4 b) {
    uint4 u;
    u.x = (unsigned)f2bf(a.x) | ((unsigned)f2bf(a.y) << 16);
    u.y = (unsigned)f2bf(a.z) | ((unsigned)f2bf(a.w) << 16);
    u.z = (unsigned)f2bf(b.x) | ((unsigned)f2bf(b.y) << 16);
    u.w = (unsigned)f2bf(b.z) | ((unsigned)f2bf(b.w) << 16);
    return u;
}

// direct global -> LDS, 16B per lane (global_load_lds_dwordx4).
__device__ __forceinline__ void gload16(const void* g, void* l) {
    __builtin_amdgcn_global_load_lds(
        (const AS1 unsigned int*)(unsigned long long)g,
        (AS3 unsigned int*)(unsigned int)(unsigned long long)l,
        16, 0, 0);
}

// ---------------------------------------------------------------------------
// Kernel 0: convert+transpose the three f32 512x512 weights into bf16
// Wt [1536][512] (n-major: Wt[n][k] = W[k][n])
// ---------------------------------------------------------------------------
__global__ void transpose512(const float* __restrict__ Wq,
                             const float* __restrict__ Wk,
                             const float* __restrict__ Wv,
                             ushort_t* __restrict__ Wt) {
    __shared__ float tile[32][33];
    int mtx = blockIdx.z;
    const float* src = (mtx == 0) ? Wq : ((mtx == 1) ? Wk : Wv);
    ushort_t* dst = Wt + (size_t)mtx * 512 * 512;
    int bx = blockIdx.x * 32, by = blockIdx.y * 32;
    int tx = threadIdx.x, ty = threadIdx.y;
    #pragma unroll
    for (int i = 0; i < 32; i += 8)
        tile[ty + i][tx] = src[(size_t)(by + ty + i) * 512 + bx + tx];
    __syncthreads();
    #pragma unroll
    for (int i = 0; i < 32; i += 8)
        dst[(size_t)(bx + ty + i) * 512 + by + tx] = f2bf(tile[tx][ty + i]);
}

// ---------------------------------------------------------------------------
// Kernel 0b: convert hidden f32 [65536,512] -> bf16 (for global_load_lds GEMM)
// ---------------------------------------------------------------------------
__global__ __launch_bounds__(256) void conv_bf16(const float* __restrict__ in,
                                                 ushort_t* __restrict__ out) {
    const size_t n8 = (size_t)BB * LL * DIMM / 8;
    const size_t stride = (size_t)gridDim.x * 256;
    for (size_t i = (size_t)blockIdx.x * 256 + threadIdx.x; i < n8; i += stride) {
        float4 lo = *((const float4*)in + 2 * i);
        float4 hi = *((const float4*)in + 2 * i + 1);
        *((uint4*)out + i) = pack8(lo, hi);
    }
}

// ---------------------------------------------------------------------------
// Kernel 1: single GEMM  C[65536,1536] = Ab[65536,512] @ Wt^T
// m97 structure: 128x128 tile, 4 waves, 4x4 mfma_16x16x32_bf16, BK=32,
// global_load_lds width-16 staging, 2 barriers per K-step, XCD chunk swizzle.
// ---------------------------------------------------------------------------
__global__ __launch_bounds__(256) void qkv_gemm_lds(
    const ushort_t* __restrict__ Ab,   // [65536, 512] bf16
    const ushort_t* __restrict__ Wt,   // [1536, 512] bf16 (W^T, q|k|v)
    const float* __restrict__ bq,
    const float* __restrict__ bk,
    const float* __restrict__ bv,
    ushort_t* __restrict__ Qo,         // [65536, 512] bf16 each
    ushort_t* __restrict__ Ko,
    ushort_t* __restrict__ Vo) {
    __shared__ ushort_t sA[128 * 32];
    __shared__ ushort_t sB[128 * 32];

    // XCD swizzle: nwg = 6144 = 8 * 768
    const int bid = blockIdx.x;
    const int lid = (bid & 7) * 768 + (bid >> 3);
    const int tn  = lid % 12;
    const int tm  = lid / 12;
    const int m0  = tm * 128;
    const int ng  = tn * 128;
    const int mtx = ng >> 9;
    const float* bias = (mtx == 0) ? bq : ((mtx == 1) ? bk : bv);
    ushort_t* Co = (mtx == 0) ? Qo : ((mtx == 1) ? Ko : Vo);
    const float scale = (mtx == 0) ? 0.125f : 1.0f;   // 1/sqrt(DH) on q
    const int n0 = ng & 511;

    const int t    = threadIdx.x;
    const int lane = t & 63;
    const int w    = t >> 6;
    const int wm   = w >> 1, wn = w & 1;
    const int md   = lane & 15, qd = lane >> 4;

    f32x4 acc[4][4];
    const f32x4 zero = {0.f, 0.f, 0.f, 0.f};
    #pragma unroll
    for (int i = 0; i < 4; ++i)
        #pragma unroll
        for (int j = 0; j < 4; ++j) acc[i][j] = zero;

    const int sr = t >> 2;
    const int sc = (t & 3) * 8;
    const ushort_t* ga0 = Ab + (size_t)(m0 + sr) * 512 + sc;
    const ushort_t* ga1 = ga0 + (size_t)64 * 512;
    const ushort_t* gb0 = Wt + (size_t)(ng + sr) * 512 + sc;
    const ushort_t* gb1 = gb0 + (size_t)64 * 512;
    ushort_t* la0 = sA + t * 8;
    ushort_t* la1 = sA + 2048 + t * 8;
    ushort_t* lb0 = sB + t * 8;
    ushort_t* lb1 = sB + 2048 + t * 8;

    const int aoff[4] = { (wm * 64 +  0 + md) * 32 + qd * 8,
                          (wm * 64 + 16 + md) * 32 + qd * 8,
                          (wm * 64 + 32 + md) * 32 + qd * 8,
                          (wm * 64 + 48 + md) * 32 + qd * 8 };
    const int boff[4] = { (wn * 64 +  0 + md) * 32 + qd * 8,
                          (wn * 64 + 16 + md) * 32 + qd * 8,
                          (wn * 64 + 32 + md) * 32 + qd * 8,
                          (wn * 64 + 48 + md) * 32 + qd * 8 };

    for (int kk = 0; kk < 16; ++kk) {
        __syncthreads();
        gload16(ga0 + kk * 32, la0);
        gload16(ga1 + kk * 32, la1);
        gload16(gb0 + kk * 32, lb0);
        gload16(gb1 + kk * 32, lb1);
        __syncthreads();

        bf16x8 af[4], bfv[4];
        #pragma unroll
        for (int mi = 0; mi < 4; ++mi) af[mi]  = *(const bf16x8*)&sA[aoff[mi]];
        #pragma unroll
        for (int ni = 0; ni < 4; ++ni) bfv[ni] = *(const bf16x8*)&sB[boff[ni]];

        #pragma unroll
        for (int mi = 0; mi < 4; ++mi)
            #pragma unroll
            for (int ni = 0; ni < 4; ++ni)
                acc[mi][ni] = __builtin_amdgcn_mfma_f32_16x16x32_bf16(
                    af[mi], bfv[ni], acc[mi][ni], 0, 0, 0);
    }

    #pragma unroll
    for (int ni = 0; ni < 4; ++ni) {
        const int col = n0 + wn * 64 + ni * 16 + md;
        const float bv_ = bias[col];
        #pragma unroll
        for (int mi = 0; mi < 4; ++mi) {
            const int rbase = m0 + wm * 64 + mi * 16 + qd * 4;
            #pragma unroll
            for (int r = 0; r < 4; ++r) {
                float v = (acc[mi][ni][r] + bv_) * scale;
                Co[(size_t)(rbase + r) * 512 + col] = f2bf(v);
            }
        }
    }
}

// ---------------------------------------------------------------------------
// Kernel 1 (fallback): per-batch register-staged GEMM
// ---------------------------------------------------------------------------
__global__ __launch_bounds__(256) void qkv_gemm(
    const float* __restrict__ A,
    const ushort_t* __restrict__ Wt,
    const float* __restrict__ bq,
    const float* __restrict__ bk,
    const float* __restrict__ bv,
    ushort_t* __restrict__ Qo,
    ushort_t* __restrict__ Ko,
    ushort_t* __restrict__ Vo) {
    __shared__ ushort_t sA[128 * 32];
    __shared__ ushort_t sB[128 * 32];

    const size_t bofs = (size_t)blockIdx.z * LL * DIMM;
    const int t  = threadIdx.x;
    const int m0 = blockIdx.y * 128;
    const int ng = blockIdx.x * 128;
    const int mtx = ng >> 9;
    const float* bias = (mtx == 0) ? bq : ((mtx == 1) ? bk : bv);
    ushort_t* Co = ((mtx == 0) ? Qo : ((mtx == 1) ? Ko : Vo)) + bofs;
    const float scale = (mtx == 0) ? 0.125f : 1.0f;
    const int n0 = ng & 511;

    const int lane = t & 63;
    const int w    = t >> 6;
    const int wm   = w >> 1, wn = w & 1;
    const int md   = lane & 15, qd = lane >> 4;

    f32x4 acc[4][4];
    const f32x4 zero = {0.f, 0.f, 0.f, 0.f};
    #pragma unroll
    for (int i = 0; i < 4; ++i)
        #pragma unroll
        for (int j = 0; j < 4; ++j) acc[i][j] = zero;

    const int ar = t >> 2;
    const int ac = (t & 3) * 8;
    const float*    gA0 = A + bofs + (size_t)(m0 + ar) * 512 + ac;
    const float*    gA1 = gA0 + (size_t)64 * 512;
    const ushort_t* gB0 = Wt + (size_t)(ng + ar) * 512 + ac;
    const ushort_t* gB1 = gB0 + (size_t)64 * 512;
    ushort_t* lA0 = sA + t * 8;
    ushort_t* lA1 = sA + 2048 + t * 8;
    ushort_t* lB0 = sB + t * 8;
    ushort_t* lB1 = sB + 2048 + t * 8;

    const int aoff[4] = { (wm * 64 +  0 + md) * 32 + qd * 8,
                          (wm * 64 + 16 + md) * 32 + qd * 8,
                          (wm * 64 + 32 + md) * 32 + qd * 8,
                          (wm * 64 + 48 + md) * 32 + qd * 8 };
    const int boff[4] = { (wn * 64 +  0 + md) * 32 + qd * 8,
                          (wn * 64 + 16 + md) * 32 + qd * 8,
                          (wn * 64 + 32 + md) * 32 + qd * 8,
                          (wn * 64 + 48 + md) * 32 + qd * 8 };

    for (int kk = 0; kk < 16; ++kk) {
        float4 a0lo = *(const float4*)(gA0 + kk * 32);
        float4 a0hi = *(const float4*)(gA0 + kk * 32 + 4);
        float4 a1lo = *(const float4*)(gA1 + kk * 32);
        float4 a1hi = *(const float4*)(gA1 + kk * 32 + 4);
        uint4 b0 = *(const uint4*)(gB0 + kk * 32);
        uint4 b1 = *(const uint4*)(gB1 + kk * 32);
        uint4 a0 = pack8(a0lo, a0hi);
        uint4 a1 = pack8(a1lo, a1hi);
        __syncthreads();
        *(uint4*)lA0 = a0;
        *(uint4*)lA1 = a1;
        *(uint4*)lB0 = b0;
        *(uint4*)lB1 = b1;
        __syncthreads();

        bf16x8 af[4], bfv[4];
        #pragma unroll
        for (int mi = 0; mi < 4; ++mi) af[mi]  = *(const bf16x8*)&sA[aoff[mi]];
        #pragma unroll
        for (int ni = 0; ni < 4; ++ni) bfv[ni] = *(const bf16x8*)&sB[boff[ni]];

        #pragma unroll
        for (int mi = 0; mi < 4; ++mi)
            #pragma unroll
            for (int ni = 0; ni < 4; ++ni)
                acc[mi][ni] = __builtin_amdgcn_mfma_f32_16x16x32_bf16(
                    af[mi], bfv[ni], acc[mi][ni], 0, 0, 0);
    }

    #pragma unroll
    for (int ni = 0; ni < 4; ++ni) {
        const int col = n0 + wn * 64 + ni * 16 + md;
        const float bv_ = bias[col];
        #pragma unroll
        for (int mi = 0; mi < 4; ++mi) {
            const int rbase = m0 + wm * 64 + mi * 16 + qd * 4;
            #pragma unroll
            for (int r = 0; r < 4; ++r) {
                float v = (acc[mi][ni][r] + bv_) * scale;
                Co[(size_t)(rbase + r) * 512 + col] = f2bf(v);
            }
        }
    }
}

// ---------------------------------------------------------------------------
// Kernel 2: NA1D attention (KS=13, dilation=2).
// 256 threads/block: lane QUAD per (l,h), each lane owns 16 of the 64 dims.
// 64 l's per block -> K/V window 88 rows, LDS 25.3 KB -> 6 blocks/CU;
// VGPR target <=128 (launch_bounds(256,4)) -> 4 waves/SIMD.  Occupancy 2x
// the round-2 kernel; per-thread serial chains halved.
// ---------------------------------------------------------------------------
__global__ __launch_bounds__(256, 4) void na1d_attn(
    const ushort_t* __restrict__ Q,     // [B][8192, 512] bf16
    const ushort_t* __restrict__ K,
    const ushort_t* __restrict__ V,
    const float* __restrict__ rpb,      // [8][25] f32
    float* __restrict__ O) {            // [B][8192, 512] f32
    __shared__ ushort_t sKV[2 * 88 * 72];   // K | V bf16 (25.3KB); f32 out overlay
    __shared__ float srpb[32];

    const int t  = threadIdx.x;
    const int l0 = blockIdx.x * 64;
    const int h  = blockIdx.y;
    const size_t bofs = (size_t)blockIdx.z * LL * DIMM;

    int p_lo = l0 - 12; if (p_lo < 0) p_lo = 0;
    int p_hi = l0 + 75; if (p_hi > LL - 1) p_hi = LL - 1;
    const int rows = p_hi - p_lo + 1;   // <= 88

    const size_t kvbase = bofs + (size_t)p_lo * DIMM + h * DH;
    const int srow = t >> 3;            // 0..31
    const int scol = (t & 7) * 8;       // bf16 elements

    ushort_t* sK = sKV;
    ushort_t* sV = sKV + 88 * 72;

    // ---- stage K and V windows (uint4 per thread; rows padded to 72) ----
    for (int r = srow; r < rows; r += 32)
        *(uint4*)&sK[r * 72 + scol] = *(const uint4*)(K + kvbase + (size_t)r * DIMM + scol);
    for (int r = srow; r < rows; r += 32)
        *(uint4*)&sV[r * 72 + scol] = *(const uint4*)(V + kvbase + (size_t)r * DIMM + scol);
    if (t < 25) srpb[t] = rpb[h * 25 + t];

    const int l    = l0 + (t >> 2);
    const int d0   = (t & 3) * 16;      // this lane's 16-dim slice
    const int par  = l & 1;
    const bool lo_e = (l < 12);
    const bool hi_e = (l + 12) >= LL;
    const int ws = lo_e ? par : (hi_e ? (LL - 26 + par) : (l - 12));
    const int ps = lo_e ? (12 - (l >> 1)) : (hi_e ? ((LL - 1 - l) >> 1) : 6);
    const int r0 = ws - p_lo;

    // ---- q (16 dims) into registers, overlapped with staging ----
    float qf[16];
    {
        const uint4* qg = (const uint4*)(Q + bofs + (size_t)l * DIMM + h * DH + d0);
        #pragma unroll
        for (int c = 0; c < 2; ++c) { uint4 u = qg[c]; unpack8(u, &qf[c * 8]); }
    }
    __syncthreads();

    // ---- scores: 16-dim partial dot, combined across the lane quad ----
    float s[13];
    #pragma unroll
    for (int j = 0; j < 13; ++j) {
        const uint4* kp = (const uint4*)&sK[(unsigned)(r0 + 2 * j) * 72 + d0];
        float a = 0.f;
        #pragma unroll
        for (int c = 0; c < 2; ++c) {
            uint4 u = kp[c]; float f[8]; unpack8(u, f);
            a += qf[c*8+0]*f[0] + qf[c*8+1]*f[1] + qf[c*8+2]*f[2] + qf[c*8+3]*f[3]
               + qf[c*8+4]*f[4] + qf[c*8+5]*f[5] + qf[c*8+6]*f[6] + qf[c*8+7]*f[7];
        }
        a += __shfl_xor(a, 1);           // combine the four 16-dim quarters
        a += __shfl_xor(a, 2);
        s[j] = a + srpb[ps + j];
    }

    // ---- softmax (duplicated across the quad; identical result) ----
    float mx = s[0];
    #pragma unroll
    for (int j = 1; j < 13; ++j) mx = fmaxf(mx, s[j]);
    float sum = 0.f;
    #pragma unroll
    for (int j = 0; j < 13; ++j) { s[j] = __expf(s[j] - mx); sum += s[j]; }
    const float inv = 1.0f / sum;
    #pragma unroll
    for (int j = 0; j < 13; ++j) s[j] *= inv;

    // ---- weighted sum over the 13 neighbors (16 dims per lane) ----
    float of[16];
    #pragma unroll
    for (int d = 0; d < 16; ++d) of[d] = 0.f;
    #pragma unroll
    for (int j = 0; j < 13; ++j) {
        const uint4* vp = (const uint4*)&sV[(unsigned)(r0 + 2 * j) * 72 + d0];
        const float wj = s[j];
        #pragma unroll
        for (int c = 0; c < 2; ++c) {
            uint4 u = vp[c]; float f[8]; unpack8(u, f);
            #pragma unroll
            for (int e = 0; e < 8; ++e) of[c * 8 + e] += wj * f[e];
        }
    }

    // ---- stage output tile in LDS (f32 [64][66] overlay) ----
    __syncthreads();                     // all K/V LDS reads done before overwrite
    float* sO = (float*)sKV;
    {
        float* orow = &sO[(t >> 2) * 66 + d0];
        #pragma unroll
        for (int c = 0; c < 4; ++c) {
            float4 v4; v4.x = of[c*4+0]; v4.y = of[c*4+1];
            v4.z = of[c*4+2]; v4.w = of[c*4+3];
            *(float4*)&orow[c * 4] = v4;
        }
    }
    __syncthreads();
    {
        const int rr = t >> 4;           // 0..15
        const int cc = (t & 15) * 4;     // 16 lanes x 16B = 256B contiguous/row
        float* Ob = O + bofs;
        #pragma unroll
        for (int r4 = 0; r4 < 4; ++r4) {
            const int r = rr + r4 * 16;
            *(float4*)(Ob + (size_t)(l0 + r) * DIMM + h * DH + cc) =
                *(const float4*)&sO[r * 66 + cc];
        }
    }
}

// ---------------------------------------------------------------------------
extern "C" void kernel_launch(void* const* d_in, const int* in_sizes, int n_in,
                              void* d_out, int out_size, void* d_ws, size_t ws_size,
                              hipStream_t stream) {
    const float* hid = (const float*)d_in[0];
    const float* Wq  = (const float*)d_in[1];
    const float* bq  = (const float*)d_in[2];
    const float* Wk  = (const float*)d_in[3];
    const float* bk  = (const float*)d_in[4];
    const float* Wv  = (const float*)d_in[5];
    const float* bv  = (const float*)d_in[6];
    const float* rpb = (const float*)d_in[7];
    float* out = (float*)d_out;

    ushort_t* ws = (ushort_t*)d_ws;
    ushort_t* Wt = ws;
    const size_t perB = (size_t)LL * DIMM;
    const size_t perF = (size_t)BB * perB;
    const size_t wtEl = (size_t)1536 * 512;
    const size_t need_new = (wtEl + 4 * perF) * sizeof(ushort_t);   // ~270 MB
    const size_t need_bat = (wtEl + 3 * perF) * sizeof(ushort_t);   // ~203 MB

    transpose512<<<dim3(16, 16, 3), dim3(32, 8), 0, stream>>>(Wq, Wk, Wv, Wt);

    if (ws_size >= need_new) {
        ushort_t* Ab = Wt + wtEl;
        ushort_t* Qb = Ab + perF;
        ushort_t* Kb = Qb + perF;
        ushort_t* Vb = Kb + perF;
        conv_bf16<<<2048, 256, 0, stream>>>(hid, Ab);
        qkv_gemm_lds<<<dim3(6144), 256, 0, stream>>>(Ab, Wt, bq, bk, bv, Qb, Kb, Vb);
        na1d_attn<<<dim3(LL / 64, HH, BB), 256, 0, stream>>>(Qb, Kb, Vb, rpb, out);
    } else if (ws_size >= need_bat) {
        ushort_t* Qb = Wt + wtEl;
        ushort_t* Kb = Qb + perF;
        ushort_t* Vb = Kb + perF;
        qkv_gemm<<<dim3(12, 64, BB), 256, 0, stream>>>(hid, Wt, bq, bk, bv, Qb, Kb, Vb);
        na1d_attn<<<dim3(LL / 64, HH, BB), 256, 0, stream>>>(Qb, Kb, Vb, rpb, out);
    } else {
        ushort_t* Qb = Wt + wtEl;
        ushort_t* Kb = Qb + perB;
        ushort_t* Vb = Kb + perB;
        for (int b = 0; b < BB; ++b) {
            const float* hb = hid + (size_t)b * perB;
            float*       ob = out + (size_t)b * perB;
            qkv_gemm<<<dim3(12, 64, 1), 256, 0, stream>>>(hb, Wt, bq, bk, bv, Qb, Kb, Vb);
            na1d_attn<<<dim3(LL / 64, HH, 1), 256, 0, stream>>>(Qb, Kb, Vb, rpb, ob);
        }
    }
}

// Round 4
// 509.338 us; speedup vs baseline: 1.4830x; 1.4830x over previous
//
#include <hip/hip_runtime.h>
#include <stdint.h>

// ---- problem constants ----
#define BB   8
#define LL   8192
#define HH   8
#define DH   64
#define DIMM 512
#define KS_  13
// dilation = 2, ns = 6

typedef unsigned short ushort_t;
typedef __attribute__((ext_vector_type(8))) short bf16x8;   // 8 x bf16 (4 VGPRs)
typedef __attribute__((ext_vector_type(4))) float f32x4;

#define AS1 __attribute__((address_space(1)))
#define AS3 __attribute__((address_space(3)))

__device__ __forceinline__ unsigned short f2bf(float f) {
    unsigned u = __float_as_uint(f);
    u += 0x7fffu + ((u >> 16) & 1u);       // round-to-nearest-even
    return (unsigned short)(u >> 16);
}
__device__ __forceinline__ void unpack8(uint4 u, float* f) {
    f[0] = __uint_as_float(u.x << 16); f[1] = __uint_as_float(u.x & 0xffff0000u);
    f[2] = __uint_as_float(u.y << 16); f[3] = __uint_as_float(u.y & 0xffff0000u);
    f[4] = __uint_as_float(u.z << 16); f[5] = __uint_as_float(u.z & 0xffff0000u);
    f[6] = __uint_as_float(u.w << 16); f[7] = __uint_as_float(u.w & 0xffff0000u);
}
__device__ __forceinline__ uint4 pack8(const float4 a, const float4 b) {
    uint4 u;
    u.x = (unsigned)f2bf(a.x) | ((unsigned)f2bf(a.y) << 16);
    u.y = (unsigned)f2bf(a.z) | ((unsigned)f2bf(a.w) << 16);
    u.z = (unsigned)f2bf(b.x) | ((unsigned)f2bf(b.y) << 16);
    u.w = (unsigned)f2bf(b.z) | ((unsigned)f2bf(b.w) << 16);
    return u;
}

// direct global -> LDS, 16B per lane (global_load_lds_dwordx4).
__device__ __forceinline__ void gload16(const void* g, void* l) {
    __builtin_amdgcn_global_load_lds(
        (const AS1 unsigned int*)(unsigned long long)g,
        (AS3 unsigned int*)(unsigned int)(unsigned long long)l,
        16, 0, 0);
}

// ---------------------------------------------------------------------------
// Kernel 0: convert+transpose the three f32 512x512 weights into bf16
// Wt [1536][512] (n-major: Wt[n][k] = W[k][n])
// ---------------------------------------------------------------------------
__global__ void transpose512(const float* __restrict__ Wq,
                             const float* __restrict__ Wk,
                             const float* __restrict__ Wv,
                             ushort_t* __restrict__ Wt) {
    __shared__ float tile[32][33];
    int mtx = blockIdx.z;
    const float* src = (mtx == 0) ? Wq : ((mtx == 1) ? Wk : Wv);
    ushort_t* dst = Wt + (size_t)mtx * 512 * 512;
    int bx = blockIdx.x * 32, by = blockIdx.y * 32;
    int tx = threadIdx.x, ty = threadIdx.y;
    #pragma unroll
    for (int i = 0; i < 32; i += 8)
        tile[ty + i][tx] = src[(size_t)(by + ty + i) * 512 + bx + tx];
    __syncthreads();
    #pragma unroll
    for (int i = 0; i < 32; i += 8)
        dst[(size_t)(bx + ty + i) * 512 + by + tx] = f2bf(tile[tx][ty + i]);
}

// ---------------------------------------------------------------------------
// Kernel 0b: convert hidden f32 [65536,512] -> bf16 (for global_load_lds GEMM)
// ---------------------------------------------------------------------------
__global__ __launch_bounds__(256) void conv_bf16(const float* __restrict__ in,
                                                 ushort_t* __restrict__ out) {
    const size_t n8 = (size_t)BB * LL * DIMM / 8;
    const size_t stride = (size_t)gridDim.x * 256;
    for (size_t i = (size_t)blockIdx.x * 256 + threadIdx.x; i < n8; i += stride) {
        float4 lo = *((const float4*)in + 2 * i);
        float4 hi = *((const float4*)in + 2 * i + 1);
        *((uint4*)out + i) = pack8(lo, hi);
    }
}

// ---------------------------------------------------------------------------
// Kernel 1: single GEMM  C[65536,1536] = Ab[65536,512] @ Wt^T
// m97 structure: 128x128 tile, 4 waves, 4x4 mfma_16x16x32_bf16, BK=32,
// global_load_lds width-16 staging, 2 barriers per K-step, XCD chunk swizzle.
// ---------------------------------------------------------------------------
__global__ __launch_bounds__(256) void qkv_gemm_lds(
    const ushort_t* __restrict__ Ab,   // [65536, 512] bf16
    const ushort_t* __restrict__ Wt,   // [1536, 512] bf16 (W^T, q|k|v)
    const float* __restrict__ bq,
    const float* __restrict__ bk,
    const float* __restrict__ bv,
    ushort_t* __restrict__ Qo,         // [65536, 512] bf16 each
    ushort_t* __restrict__ Ko,
    ushort_t* __restrict__ Vo) {
    __shared__ ushort_t sA[128 * 32];
    __shared__ ushort_t sB[128 * 32];

    // XCD swizzle: nwg = 6144 = 8 * 768
    const int bid = blockIdx.x;
    const int lid = (bid & 7) * 768 + (bid >> 3);
    const int tn  = lid % 12;
    const int tm  = lid / 12;
    const int m0  = tm * 128;
    const int ng  = tn * 128;
    const int mtx = ng >> 9;
    const float* bias = (mtx == 0) ? bq : ((mtx == 1) ? bk : bv);
    ushort_t* Co = (mtx == 0) ? Qo : ((mtx == 1) ? Ko : Vo);
    const float scale = (mtx == 0) ? 0.125f : 1.0f;   // 1/sqrt(DH) on q
    const int n0 = ng & 511;

    const int t    = threadIdx.x;
    const int lane = t & 63;
    const int w    = t >> 6;
    const int wm   = w >> 1, wn = w & 1;
    const int md   = lane & 15, qd = lane >> 4;

    f32x4 acc[4][4];
    const f32x4 zero = {0.f, 0.f, 0.f, 0.f};
    #pragma unroll
    for (int i = 0; i < 4; ++i)
        #pragma unroll
        for (int j = 0; j < 4; ++j) acc[i][j] = zero;

    const int sr = t >> 2;
    const int sc = (t & 3) * 8;
    const ushort_t* ga0 = Ab + (size_t)(m0 + sr) * 512 + sc;
    const ushort_t* ga1 = ga0 + (size_t)64 * 512;
    const ushort_t* gb0 = Wt + (size_t)(ng + sr) * 512 + sc;
    const ushort_t* gb1 = gb0 + (size_t)64 * 512;
    ushort_t* la0 = sA + t * 8;
    ushort_t* la1 = sA + 2048 + t * 8;
    ushort_t* lb0 = sB + t * 8;
    ushort_t* lb1 = sB + 2048 + t * 8;

    const int aoff[4] = { (wm * 64 +  0 + md) * 32 + qd * 8,
                          (wm * 64 + 16 + md) * 32 + qd * 8,
                          (wm * 64 + 32 + md) * 32 + qd * 8,
                          (wm * 64 + 48 + md) * 32 + qd * 8 };
    const int boff[4] = { (wn * 64 +  0 + md) * 32 + qd * 8,
                          (wn * 64 + 16 + md) * 32 + qd * 8,
                          (wn * 64 + 32 + md) * 32 + qd * 8,
                          (wn * 64 + 48 + md) * 32 + qd * 8 };

    for (int kk = 0; kk < 16; ++kk) {
        __syncthreads();
        gload16(ga0 + kk * 32, la0);
        gload16(ga1 + kk * 32, la1);
        gload16(gb0 + kk * 32, lb0);
        gload16(gb1 + kk * 32, lb1);
        __syncthreads();

        bf16x8 af[4], bfv[4];
        #pragma unroll
        for (int mi = 0; mi < 4; ++mi) af[mi]  = *(const bf16x8*)&sA[aoff[mi]];
        #pragma unroll
        for (int ni = 0; ni < 4; ++ni) bfv[ni] = *(const bf16x8*)&sB[boff[ni]];

        #pragma unroll
        for (int mi = 0; mi < 4; ++mi)
            #pragma unroll
            for (int ni = 0; ni < 4; ++ni)
                acc[mi][ni] = __builtin_amdgcn_mfma_f32_16x16x32_bf16(
                    af[mi], bfv[ni], acc[mi][ni], 0, 0, 0);
    }

    #pragma unroll
    for (int ni = 0; ni < 4; ++ni) {
        const int col = n0 + wn * 64 + ni * 16 + md;
        const float bv_ = bias[col];
        #pragma unroll
        for (int mi = 0; mi < 4; ++mi) {
            const int rbase = m0 + wm * 64 + mi * 16 + qd * 4;
            #pragma unroll
            for (int r = 0; r < 4; ++r) {
                float v = (acc[mi][ni][r] + bv_) * scale;
                Co[(size_t)(rbase + r) * 512 + col] = f2bf(v);
            }
        }
    }
}

// ---------------------------------------------------------------------------
// Kernel 1 (fallback): per-batch register-staged GEMM
// ---------------------------------------------------------------------------
__global__ __launch_bounds__(256) void qkv_gemm(
    const float* __restrict__ A,
    const ushort_t* __restrict__ Wt,
    const float* __restrict__ bq,
    const float* __restrict__ bk,
    const float* __restrict__ bv,
    ushort_t* __restrict__ Qo,
    ushort_t* __restrict__ Ko,
    ushort_t* __restrict__ Vo) {
    __shared__ ushort_t sA[128 * 32];
    __shared__ ushort_t sB[128 * 32];

    const size_t bofs = (size_t)blockIdx.z * LL * DIMM;
    const int t  = threadIdx.x;
    const int m0 = blockIdx.y * 128;
    const int ng = blockIdx.x * 128;
    const int mtx = ng >> 9;
    const float* bias = (mtx == 0) ? bq : ((mtx == 1) ? bk : bv);
    ushort_t* Co = ((mtx == 0) ? Qo : ((mtx == 1) ? Ko : Vo)) + bofs;
    const float scale = (mtx == 0) ? 0.125f : 1.0f;
    const int n0 = ng & 511;

    const int lane = t & 63;
    const int w    = t >> 6;
    const int wm   = w >> 1, wn = w & 1;
    const int md   = lane & 15, qd = lane >> 4;

    f32x4 acc[4][4];
    const f32x4 zero = {0.f, 0.f, 0.f, 0.f};
    #pragma unroll
    for (int i = 0; i < 4; ++i)
        #pragma unroll
        for (int j = 0; j < 4; ++j) acc[i][j] = zero;

    const int ar = t >> 2;
    const int ac = (t & 3) * 8;
    const float*    gA0 = A + bofs + (size_t)(m0 + ar) * 512 + ac;
    const float*    gA1 = gA0 + (size_t)64 * 512;
    const ushort_t* gB0 = Wt + (size_t)(ng + ar) * 512 + ac;
    const ushort_t* gB1 = gB0 + (size_t)64 * 512;
    ushort_t* lA0 = sA + t * 8;
    ushort_t* lA1 = sA + 2048 + t * 8;
    ushort_t* lB0 = sB + t * 8;
    ushort_t* lB1 = sB + 2048 + t * 8;

    const int aoff[4] = { (wm * 64 +  0 + md) * 32 + qd * 8,
                          (wm * 64 + 16 + md) * 32 + qd * 8,
                          (wm * 64 + 32 + md) * 32 + qd * 8,
                          (wm * 64 + 48 + md) * 32 + qd * 8 };
    const int boff[4] = { (wn * 64 +  0 + md) * 32 + qd * 8,
                          (wn * 64 + 16 + md) * 32 + qd * 8,
                          (wn * 64 + 32 + md) * 32 + qd * 8,
                          (wn * 64 + 48 + md) * 32 + qd * 8 };

    for (int kk = 0; kk < 16; ++kk) {
        float4 a0lo = *(const float4*)(gA0 + kk * 32);
        float4 a0hi = *(const float4*)(gA0 + kk * 32 + 4);
        float4 a1lo = *(const float4*)(gA1 + kk * 32);
        float4 a1hi = *(const float4*)(gA1 + kk * 32 + 4);
        uint4 b0 = *(const uint4*)(gB0 + kk * 32);
        uint4 b1 = *(const uint4*)(gB1 + kk * 32);
        uint4 a0 = pack8(a0lo, a0hi);
        uint4 a1 = pack8(a1lo, a1hi);
        __syncthreads();
        *(uint4*)lA0 = a0;
        *(uint4*)lA1 = a1;
        *(uint4*)lB0 = b0;
        *(uint4*)lB1 = b1;
        __syncthreads();

        bf16x8 af[4], bfv[4];
        #pragma unroll
        for (int mi = 0; mi < 4; ++mi) af[mi]  = *(const bf16x8*)&sA[aoff[mi]];
        #pragma unroll
        for (int ni = 0; ni < 4; ++ni) bfv[ni] = *(const bf16x8*)&sB[boff[ni]];

        #pragma unroll
        for (int mi = 0; mi < 4; ++mi)
            #pragma unroll
            for (int ni = 0; ni < 4; ++ni)
                acc[mi][ni] = __builtin_amdgcn_mfma_f32_16x16x32_bf16(
                    af[mi], bfv[ni], acc[mi][ni], 0, 0, 0);
    }

    #pragma unroll
    for (int ni = 0; ni < 4; ++ni) {
        const int col = n0 + wn * 64 + ni * 16 + md;
        const float bv_ = bias[col];
        #pragma unroll
        for (int mi = 0; mi < 4; ++mi) {
            const int rbase = m0 + wm * 64 + mi * 16 + qd * 4;
            #pragma unroll
            for (int r = 0; r < 4; ++r) {
                float v = (acc[mi][ni][r] + bv_) * scale;
                Co[(size_t)(rbase + r) * 512 + col] = f2bf(v);
            }
        }
    }
}

// ---------------------------------------------------------------------------
// Kernel 2: NA1D attention (KS=13, dilation=2).
// 256 threads/block: lane QUAD per (l,h), each lane owns 16 of the 64 dims.
// 64 l's per block -> K/V window 88 rows, LDS 25.3 KB.
// NOTE: plain __launch_bounds__(256) — round 3's (256,4) min-wave bound
// forced a 64-VGPR allocation that spilled qf/of/s to scratch (WRITE_SIZE
// 128 MiB -> 864 MiB, FETCH +386 MB, VALUBusy 21->13%).  Let the allocator
// take ~110-130 VGPRs; HW still gets 4 waves/SIMD at that count.
// ---------------------------------------------------------------------------
__global__ __launch_bounds__(256) void na1d_attn(
    const ushort_t* __restrict__ Q,     // [B][8192, 512] bf16
    const ushort_t* __restrict__ K,
    const ushort_t* __restrict__ V,
    const float* __restrict__ rpb,      // [8][25] f32
    float* __restrict__ O) {            // [B][8192, 512] f32
    __shared__ ushort_t sKV[2 * 88 * 72];   // K | V bf16 (25.3KB); f32 out overlay
    __shared__ float srpb[32];

    const int t  = threadIdx.x;
    const int l0 = blockIdx.x * 64;
    const int h  = blockIdx.y;
    const size_t bofs = (size_t)blockIdx.z * LL * DIMM;

    int p_lo = l0 - 12; if (p_lo < 0) p_lo = 0;
    int p_hi = l0 + 75; if (p_hi > LL - 1) p_hi = LL - 1;
    const int rows = p_hi - p_lo + 1;   // <= 88

    const size_t kvbase = bofs + (size_t)p_lo * DIMM + h * DH;
    const int srow = t >> 3;            // 0..31
    const int scol = (t & 7) * 8;       // bf16 elements

    ushort_t* sK = sKV;
    ushort_t* sV = sKV + 88 * 72;

    // ---- stage K and V windows (uint4 per thread; rows padded to 72) ----
    for (int r = srow; r < rows; r += 32)
        *(uint4*)&sK[r * 72 + scol] = *(const uint4*)(K + kvbase + (size_t)r * DIMM + scol);
    for (int r = srow; r < rows; r += 32)
        *(uint4*)&sV[r * 72 + scol] = *(const uint4*)(V + kvbase + (size_t)r * DIMM + scol);
    if (t < 25) srpb[t] = rpb[h * 25 + t];

    const int l    = l0 + (t >> 2);
    const int d0   = (t & 3) * 16;      // this lane's 16-dim slice
    const int par  = l & 1;
    const bool lo_e = (l < 12);
    const bool hi_e = (l + 12) >= LL;
    const int ws = lo_e ? par : (hi_e ? (LL - 26 + par) : (l - 12));
    const int ps = lo_e ? (12 - (l >> 1)) : (hi_e ? ((LL - 1 - l) >> 1) : 6);
    const int r0 = ws - p_lo;

    // ---- q (16 dims) into registers, overlapped with staging ----
    float qf[16];
    {
        const uint4* qg = (const uint4*)(Q + bofs + (size_t)l * DIMM + h * DH + d0);
        #pragma unroll
        for (int c = 0; c < 2; ++c) { uint4 u = qg[c]; unpack8(u, &qf[c * 8]); }
    }
    __syncthreads();

    // ---- scores: 16-dim partial dot, combined across the lane quad ----
    float s[13];
    #pragma unroll
    for (int j = 0; j < 13; ++j) {
        const uint4* kp = (const uint4*)&sK[(unsigned)(r0 + 2 * j) * 72 + d0];
        float a = 0.f;
        #pragma unroll
        for (int c = 0; c < 2; ++c) {
            uint4 u = kp[c]; float f[8]; unpack8(u, f);
            a += qf[c*8+0]*f[0] + qf[c*8+1]*f[1] + qf[c*8+2]*f[2] + qf[c*8+3]*f[3]
               + qf[c*8+4]*f[4] + qf[c*8+5]*f[5] + qf[c*8+6]*f[6] + qf[c*8+7]*f[7];
        }
        a += __shfl_xor(a, 1);           // combine the four 16-dim quarters
        a += __shfl_xor(a, 2);
        s[j] = a + srpb[ps + j];
    }

    // ---- softmax (duplicated across the quad; identical result) ----
    float mx = s[0];
    #pragma unroll
    for (int j = 1; j < 13; ++j) mx = fmaxf(mx, s[j]);
    float sum = 0.f;
    #pragma unroll
    for (int j = 0; j < 13; ++j) { s[j] = __expf(s[j] - mx); sum += s[j]; }
    const float inv = 1.0f / sum;
    #pragma unroll
    for (int j = 0; j < 13; ++j) s[j] *= inv;

    // ---- weighted sum over the 13 neighbors (16 dims per lane) ----
    float of[16];
    #pragma unroll
    for (int d = 0; d < 16; ++d) of[d] = 0.f;
    #pragma unroll
    for (int j = 0; j < 13; ++j) {
        const uint4* vp = (const uint4*)&sV[(unsigned)(r0 + 2 * j) * 72 + d0];
        const float wj = s[j];
        #pragma unroll
        for (int c = 0; c < 2; ++c) {
            uint4 u = vp[c]; float f[8]; unpack8(u, f);
            #pragma unroll
            for (int e = 0; e < 8; ++e) of[c * 8 + e] += wj * f[e];
        }
    }

    // ---- stage output tile in LDS (f32 [64][66] overlay) ----
    __syncthreads();                     // all K/V LDS reads done before overwrite
    float* sO = (float*)sKV;
    {
        float* orow = &sO[(t >> 2) * 66 + d0];
        #pragma unroll
        for (int c = 0; c < 4; ++c) {
            float4 v4; v4.x = of[c*4+0]; v4.y = of[c*4+1];
            v4.z = of[c*4+2]; v4.w = of[c*4+3];
            *(float4*)&orow[c * 4] = v4;
        }
    }
    __syncthreads();
    {
        const int rr = t >> 4;           // 0..15
        const int cc = (t & 15) * 4;     // 16 lanes x 16B = 256B contiguous/row
        float* Ob = O + bofs;
        #pragma unroll
        for (int r4 = 0; r4 < 4; ++r4) {
            const int r = rr + r4 * 16;
            *(float4*)(Ob + (size_t)(l0 + r) * DIMM + h * DH + cc) =
                *(const float4*)&sO[r * 66 + cc];
        }
    }
}

// ---------------------------------------------------------------------------
extern "C" void kernel_launch(void* const* d_in, const int* in_sizes, int n_in,
                              void* d_out, int out_size, void* d_ws, size_t ws_size,
                              hipStream_t stream) {
    const float* hid = (const float*)d_in[0];
    const float* Wq  = (const float*)d_in[1];
    const float* bq  = (const float*)d_in[2];
    const float* Wk  = (const float*)d_in[3];
    const float* bk  = (const float*)d_in[4];
    const float* Wv  = (const float*)d_in[5];
    const float* bv  = (const float*)d_in[6];
    const float* rpb = (const float*)d_in[7];
    float* out = (float*)d_out;

    ushort_t* ws = (ushort_t*)d_ws;
    ushort_t* Wt = ws;
    const size_t perB = (size_t)LL * DIMM;
    const size_t perF = (size_t)BB * perB;
    const size_t wtEl = (size_t)1536 * 512;
    const size_t need_new = (wtEl + 4 * perF) * sizeof(ushort_t);   // ~270 MB
    const size_t need_bat = (wtEl + 3 * perF) * sizeof(ushort_t);   // ~203 MB

    transpose512<<<dim3(16, 16, 3), dim3(32, 8), 0, stream>>>(Wq, Wk, Wv, Wt);

    if (ws_size >= need_new) {
        ushort_t* Ab = Wt + wtEl;
        ushort_t* Qb = Ab + perF;
        ushort_t* Kb = Qb + perF;
        ushort_t* Vb = Kb + perF;
        conv_bf16<<<2048, 256, 0, stream>>>(hid, Ab);
        qkv_gemm_lds<<<dim3(6144), 256, 0, stream>>>(Ab, Wt, bq, bk, bv, Qb, Kb, Vb);
        na1d_attn<<<dim3(LL / 64, HH, BB), 256, 0, stream>>>(Qb, Kb, Vb, rpb, out);
    } else if (ws_size >= need_bat) {
        ushort_t* Qb = Wt + wtEl;
        ushort_t* Kb = Qb + perF;
        ushort_t* Vb = Kb + perF;
        qkv_gemm<<<dim3(12, 64, BB), 256, 0, stream>>>(hid, Wt, bq, bk, bv, Qb, Kb, Vb);
        na1d_attn<<<dim3(LL / 64, HH, BB), 256, 0, stream>>>(Qb, Kb, Vb, rpb, out);
    } else {
        ushort_t* Qb = Wt + wtEl;
        ushort_t* Kb = Qb + perB;
        ushort_t* Vb = Kb + perB;
        for (int b = 0; b < BB; ++b) {
            const float* hb = hid + (size_t)b * perB;
            float*       ob = out + (size_t)b * perB;
            qkv_gemm<<<dim3(12, 64, 1), 256, 0, stream>>>(hb, Wt, bq, bk, bv, Qb, Kb, Vb);
            na1d_attn<<<dim3(LL / 64, HH, 1), 256, 0, stream>>>(Qb, Kb, Vb, rpb, ob);
        }
    }
}

// Round 5
// 494.085 us; speedup vs baseline: 1.5288x; 1.0309x over previous
//
#include <hip/hip_runtime.h>
#include <stdint.h>

// ---- problem constants ----
#define BB   8
#define LL   8192
#define HH   8
#define DH   64
#define DIMM 512
#define KS_  13
// dilation = 2, ns = 6

typedef unsigned short ushort_t;
typedef __attribute__((ext_vector_type(8))) short bf16x8;   // 8 x bf16 (4 VGPRs)
typedef __attribute__((ext_vector_type(4))) float f32x4;

#define AS1 __attribute__((address_space(1)))
#define AS3 __attribute__((address_space(3)))

__device__ __forceinline__ unsigned short f2bf(float f) {
    unsigned u = __float_as_uint(f);
    u += 0x7fffu + ((u >> 16) & 1u);       // round-to-nearest-even
    return (unsigned short)(u >> 16);
}
__device__ __forceinline__ void unpack8(uint4 u, float* f) {
    f[0] = __uint_as_float(u.x << 16); f[1] = __uint_as_float(u.x & 0xffff0000u);
    f[2] = __uint_as_float(u.y << 16); f[3] = __uint_as_float(u.y & 0xffff0000u);
    f[4] = __uint_as_float(u.z << 16); f[5] = __uint_as_float(u.z & 0xffff0000u);
    f[6] = __uint_as_float(u.w << 16); f[7] = __uint_as_float(u.w & 0xffff0000u);
}
__device__ __forceinline__ uint4 pack8(const float4 a, const float4 b) {
    uint4 u;
    u.x = (unsigned)f2bf(a.x) | ((unsigned)f2bf(a.y) << 16);
    u.y = (unsigned)f2bf(a.z) | ((unsigned)f2bf(a.w) << 16);
    u.z = (unsigned)f2bf(b.x) | ((unsigned)f2bf(b.y) << 16);
    u.w = (unsigned)f2bf(b.z) | ((unsigned)f2bf(b.w) << 16);
    return u;
}

// direct global -> LDS, 16B per lane (global_load_lds_dwordx4).
__device__ __forceinline__ void gload16(const void* g, void* l) {
    __builtin_amdgcn_global_load_lds(
        (const AS1 unsigned int*)(unsigned long long)g,
        (AS3 unsigned int*)(unsigned int)(unsigned long long)l,
        16, 0, 0);
}

// ---------------------------------------------------------------------------
// Kernel 0: convert+transpose the three f32 512x512 weights into bf16
// Wt [1536][512] (n-major: Wt[n][k] = W[k][n])
// ---------------------------------------------------------------------------
__global__ void transpose512(const float* __restrict__ Wq,
                             const float* __restrict__ Wk,
                             const float* __restrict__ Wv,
                             ushort_t* __restrict__ Wt) {
    __shared__ float tile[32][33];
    int mtx = blockIdx.z;
    const float* src = (mtx == 0) ? Wq : ((mtx == 1) ? Wk : Wv);
    ushort_t* dst = Wt + (size_t)mtx * 512 * 512;
    int bx = blockIdx.x * 32, by = blockIdx.y * 32;
    int tx = threadIdx.x, ty = threadIdx.y;
    #pragma unroll
    for (int i = 0; i < 32; i += 8)
        tile[ty + i][tx] = src[(size_t)(by + ty + i) * 512 + bx + tx];
    __syncthreads();
    #pragma unroll
    for (int i = 0; i < 32; i += 8)
        dst[(size_t)(bx + ty + i) * 512 + by + tx] = f2bf(tile[tx][ty + i]);
}

// ---------------------------------------------------------------------------
// Kernel 0b: convert hidden f32 [65536,512] -> bf16 (for global_load_lds GEMM)
// ---------------------------------------------------------------------------
__global__ __launch_bounds__(256) void conv_bf16(const float* __restrict__ in,
                                                 ushort_t* __restrict__ out) {
    const size_t n8 = (size_t)BB * LL * DIMM / 8;
    const size_t stride = (size_t)gridDim.x * 256;
    for (size_t i = (size_t)blockIdx.x * 256 + threadIdx.x; i < n8; i += stride) {
        float4 lo = *((const float4*)in + 2 * i);
        float4 hi = *((const float4*)in + 2 * i + 1);
        *((uint4*)out + i) = pack8(lo, hi);
    }
}

// ---------------------------------------------------------------------------
// Kernel 1: single GEMM  C[65536,1536] = Ab[65536,512] @ Wt^T
// 128x128 tile, 4 waves, 4x4 mfma_16x16x32_bf16, BK=32, global_load_lds
// width-16 staging.  v5: DOUBLE-BUFFERED 2-phase pipeline (T3 minimum):
// issue next K-tile's global_load_lds BEFORE current tile's ds_read+MFMA,
// ONE barrier per K-step at the end (its implicit vmcnt(0) drain now sits
// ~250 compute-cycles after load issue instead of 0).  XCD chunk swizzle.
// ---------------------------------------------------------------------------
__global__ __launch_bounds__(256) void qkv_gemm_lds(
    const ushort_t* __restrict__ Ab,   // [65536, 512] bf16
    const ushort_t* __restrict__ Wt,   // [1536, 512] bf16 (W^T, q|k|v)
    const float* __restrict__ bq,
    const float* __restrict__ bk,
    const float* __restrict__ bv,
    ushort_t* __restrict__ Qo,         // [65536, 512] bf16 each
    ushort_t* __restrict__ Ko,
    ushort_t* __restrict__ Vo) {
    __shared__ ushort_t sA[2 * 128 * 32];   // 2 buffers x 8KB
    __shared__ ushort_t sB[2 * 128 * 32];

    // XCD swizzle: nwg = 6144 = 8 * 768
    const int bid = blockIdx.x;
    const int lid = (bid & 7) * 768 + (bid >> 3);
    const int tn  = lid % 12;
    const int tm  = lid / 12;
    const int m0  = tm * 128;
    const int ng  = tn * 128;
    const int mtx = ng >> 9;
    const float* bias = (mtx == 0) ? bq : ((mtx == 1) ? bk : bv);
    ushort_t* Co = (mtx == 0) ? Qo : ((mtx == 1) ? Ko : Vo);
    const float scale = (mtx == 0) ? 0.125f : 1.0f;   // 1/sqrt(DH) on q
    const int n0 = ng & 511;

    const int t    = threadIdx.x;
    const int lane = t & 63;
    const int w    = t >> 6;
    const int wm   = w >> 1, wn = w & 1;
    const int md   = lane & 15, qd = lane >> 4;

    f32x4 acc[4][4];
    const f32x4 zero = {0.f, 0.f, 0.f, 0.f};
    #pragma unroll
    for (int i = 0; i < 4; ++i)
        #pragma unroll
        for (int j = 0; j < 4; ++j) acc[i][j] = zero;

    const int sr = t >> 2;
    const int sc = (t & 3) * 8;
    const ushort_t* ga0 = Ab + (size_t)(m0 + sr) * 512 + sc;
    const ushort_t* ga1 = ga0 + (size_t)64 * 512;
    const ushort_t* gb0 = Wt + (size_t)(ng + sr) * 512 + sc;
    const ushort_t* gb1 = gb0 + (size_t)64 * 512;
    const int ld0 = t * 8;             // element offsets within a buffer
    const int ld1 = 2048 + t * 8;

    const int aoff[4] = { (wm * 64 +  0 + md) * 32 + qd * 8,
                          (wm * 64 + 16 + md) * 32 + qd * 8,
                          (wm * 64 + 32 + md) * 32 + qd * 8,
                          (wm * 64 + 48 + md) * 32 + qd * 8 };
    const int boff[4] = { (wn * 64 +  0 + md) * 32 + qd * 8,
                          (wn * 64 + 16 + md) * 32 + qd * 8,
                          (wn * 64 + 32 + md) * 32 + qd * 8,
                          (wn * 64 + 48 + md) * 32 + qd * 8 };

    // prologue: stage K-tile 0 into buffer 0
    gload16(ga0, sA + ld0);
    gload16(ga1, sA + ld1);
    gload16(gb0, sB + ld0);
    gload16(gb1, sB + ld1);
    __syncthreads();                        // drains vmcnt(0)

    for (int kk = 0; kk < 16; ++kk) {
        const int cur = (kk & 1) << 12;     // 0 or 4096 elements
        const int nxt = 4096 - cur;
        if (kk < 15) {                      // issue next tile FIRST (uniform)
            gload16(ga0 + (kk + 1) * 32, sA + nxt + ld0);
            gload16(ga1 + (kk + 1) * 32, sA + nxt + ld1);
            gload16(gb0 + (kk + 1) * 32, sB + nxt + ld0);
            gload16(gb1 + (kk + 1) * 32, sB + nxt + ld1);
        }

        bf16x8 af[4], bfv[4];
        #pragma unroll
        for (int mi = 0; mi < 4; ++mi) af[mi]  = *(const bf16x8*)&sA[cur + aoff[mi]];
        #pragma unroll
        for (int ni = 0; ni < 4; ++ni) bfv[ni] = *(const bf16x8*)&sB[cur + boff[ni]];

        #pragma unroll
        for (int mi = 0; mi < 4; ++mi)
            #pragma unroll
            for (int ni = 0; ni < 4; ++ni)
                acc[mi][ni] = __builtin_amdgcn_mfma_f32_16x16x32_bf16(
                    af[mi], bfv[ni], acc[mi][ni], 0, 0, 0);

        __syncthreads();                    // one barrier/K-step; drains next loads
    }

    // epilogue: D[row][col], row = qd*4 + r, col = md (verified m89/m91 layout)
    #pragma unroll
    for (int ni = 0; ni < 4; ++ni) {
        const int col = n0 + wn * 64 + ni * 16 + md;
        const float bv_ = bias[col];
        #pragma unroll
        for (int mi = 0; mi < 4; ++mi) {
            const int rbase = m0 + wm * 64 + mi * 16 + qd * 4;
            #pragma unroll
            for (int r = 0; r < 4; ++r) {
                float v = (acc[mi][ni][r] + bv_) * scale;
                Co[(size_t)(rbase + r) * 512 + col] = f2bf(v);
            }
        }
    }
}

// ---------------------------------------------------------------------------
// Kernel 1 (fallback): per-batch register-staged GEMM
// ---------------------------------------------------------------------------
__global__ __launch_bounds__(256) void qkv_gemm(
    const float* __restrict__ A,
    const ushort_t* __restrict__ Wt,
    const float* __restrict__ bq,
    const float* __restrict__ bk,
    const float* __restrict__ bv,
    ushort_t* __restrict__ Qo,
    ushort_t* __restrict__ Ko,
    ushort_t* __restrict__ Vo) {
    __shared__ ushort_t sA[128 * 32];
    __shared__ ushort_t sB[128 * 32];

    const size_t bofs = (size_t)blockIdx.z * LL * DIMM;
    const int t  = threadIdx.x;
    const int m0 = blockIdx.y * 128;
    const int ng = blockIdx.x * 128;
    const int mtx = ng >> 9;
    const float* bias = (mtx == 0) ? bq : ((mtx == 1) ? bk : bv);
    ushort_t* Co = ((mtx == 0) ? Qo : ((mtx == 1) ? Ko : Vo)) + bofs;
    const float scale = (mtx == 0) ? 0.125f : 1.0f;
    const int n0 = ng & 511;

    const int lane = t & 63;
    const int w    = t >> 6;
    const int wm   = w >> 1, wn = w & 1;
    const int md   = lane & 15, qd = lane >> 4;

    f32x4 acc[4][4];
    const f32x4 zero = {0.f, 0.f, 0.f, 0.f};
    #pragma unroll
    for (int i = 0; i < 4; ++i)
        #pragma unroll
        for (int j = 0; j < 4; ++j) acc[i][j] = zero;

    const int ar = t >> 2;
    const int ac = (t & 3) * 8;
    const float*    gA0 = A + bofs + (size_t)(m0 + ar) * 512 + ac;
    const float*    gA1 = gA0 + (size_t)64 * 512;
    const ushort_t* gB0 = Wt + (size_t)(ng + ar) * 512 + ac;
    const ushort_t* gB1 = gB0 + (size_t)64 * 512;
    ushort_t* lA0 = sA + t * 8;
    ushort_t* lA1 = sA + 2048 + t * 8;
    ushort_t* lB0 = sB + t * 8;
    ushort_t* lB1 = sB + 2048 + t * 8;

    const int aoff[4] = { (wm * 64 +  0 + md) * 32 + qd * 8,
                          (wm * 64 + 16 + md) * 32 + qd * 8,
                          (wm * 64 + 32 + md) * 32 + qd * 8,
                          (wm * 64 + 48 + md) * 32 + qd * 8 };
    const int boff[4] = { (wn * 64 +  0 + md) * 32 + qd * 8,
                          (wn * 64 + 16 + md) * 32 + qd * 8,
                          (wn * 64 + 32 + md) * 32 + qd * 8,
                          (wn * 64 + 48 + md) * 32 + qd * 8 };

    for (int kk = 0; kk < 16; ++kk) {
        float4 a0lo = *(const float4*)(gA0 + kk * 32);
        float4 a0hi = *(const float4*)(gA0 + kk * 32 + 4);
        float4 a1lo = *(const float4*)(gA1 + kk * 32);
        float4 a1hi = *(const float4*)(gA1 + kk * 32 + 4);
        uint4 b0 = *(const uint4*)(gB0 + kk * 32);
        uint4 b1 = *(const uint4*)(gB1 + kk * 32);
        uint4 a0 = pack8(a0lo, a0hi);
        uint4 a1 = pack8(a1lo, a1hi);
        __syncthreads();
        *(uint4*)lA0 = a0;
        *(uint4*)lA1 = a1;
        *(uint4*)lB0 = b0;
        *(uint4*)lB1 = b1;
        __syncthreads();

        bf16x8 af[4], bfv[4];
        #pragma unroll
        for (int mi = 0; mi < 4; ++mi) af[mi]  = *(const bf16x8*)&sA[aoff[mi]];
        #pragma unroll
        for (int ni = 0; ni < 4; ++ni) bfv[ni] = *(const bf16x8*)&sB[boff[ni]];

        #pragma unroll
        for (int mi = 0; mi < 4; ++mi)
            #pragma unroll
            for (int ni = 0; ni < 4; ++ni)
                acc[mi][ni] = __builtin_amdgcn_mfma_f32_16x16x32_bf16(
                    af[mi], bfv[ni], acc[mi][ni], 0, 0, 0);
    }

    #pragma unroll
    for (int ni = 0; ni < 4; ++ni) {
        const int col = n0 + wn * 64 + ni * 16 + md;
        const float bv_ = bias[col];
        #pragma unroll
        for (int mi = 0; mi < 4; ++mi) {
            const int rbase = m0 + wm * 64 + mi * 16 + qd * 4;
            #pragma unroll
            for (int r = 0; r < 4; ++r) {
                float v = (acc[mi][ni][r] + bv_) * scale;
                Co[(size_t)(rbase + r) * 512 + col] = f2bf(v);
            }
        }
    }
}

// ---------------------------------------------------------------------------
// Kernel 2: NA1D attention (KS=13, dilation=2), v4.
// 256 threads/block, lane QUAD per (l,h), 16 dims/lane, 64 l's per block.
// NO K/V LDS staging: per-block K/V head-slices are ~11KB with 13x reuse ->
// L1/L2-resident; direct global reads kill the two staging barriers and the
// serial HBM stage (Common-mistake #7).  Output still goes through an LDS
// overlay so every global store writes full lines (keeps WRITE at ideal).
// ---------------------------------------------------------------------------
__global__ __launch_bounds__(256) void na1d_attn(
    const ushort_t* __restrict__ Q,     // [B][8192, 512] bf16
    const ushort_t* __restrict__ K,
    const ushort_t* __restrict__ V,
    const float* __restrict__ rpb,      // [8][25] f32
    float* __restrict__ O) {            // [B][8192, 512] f32
    __shared__ float sO[64 * 66];       // 16.9 KB output overlay
    __shared__ float srpb[32];

    const int t  = threadIdx.x;
    const int l0 = blockIdx.x * 64;
    const int h  = blockIdx.y;
    const size_t bofs = (size_t)blockIdx.z * LL * DIMM;

    if (t < 25) srpb[t] = rpb[h * 25 + t];

    const int l    = l0 + (t >> 2);
    const int d0   = (t & 3) * 16;      // this lane's 16-dim slice
    const int par  = l & 1;
    const bool lo_e = (l < 12);
    const bool hi_e = (l + 12) >= LL;
    const int ws = lo_e ? par : (hi_e ? (LL - 26 + par) : (l - 12));
    const int ps = lo_e ? (12 - (l >> 1)) : (hi_e ? ((LL - 1 - l) >> 1) : 6);

    const ushort_t* kbase = K + bofs + (size_t)ws * DIMM + h * DH + d0;
    const ushort_t* vbase = V + bofs + (size_t)ws * DIMM + h * DH + d0;

    // ---- q (16 dims) into registers ----
    float qf[16];
    {
        const uint4* qg = (const uint4*)(Q + bofs + (size_t)l * DIMM + h * DH + d0);
        unpack8(qg[0], qf);
        unpack8(qg[1], qf + 8);
    }
    __syncthreads();                    // srpb visible

    // ---- scores: 16-dim partial dot from global (L1/L2-hit), quad combine ----
    float s[13];
    #pragma unroll
    for (int j = 0; j < 13; ++j) {
        const uint4* kp = (const uint4*)(kbase + (size_t)(2 * j) * DIMM);
        uint4 u0 = kp[0], u1 = kp[1];
        float f[8];
        float a = 0.f;
        unpack8(u0, f);
        a += qf[0]*f[0] + qf[1]*f[1] + qf[2]*f[2] + qf[3]*f[3]
           + qf[4]*f[4] + qf[5]*f[5] + qf[6]*f[6] + qf[7]*f[7];
        unpack8(u1, f);
        a += qf[8]*f[0] + qf[9]*f[1] + qf[10]*f[2] + qf[11]*f[3]
           + qf[12]*f[4] + qf[13]*f[5] + qf[14]*f[6] + qf[15]*f[7];
        a += __shfl_xor(a, 1);          // combine the four 16-dim quarters
        a += __shfl_xor(a, 2);
        s[j] = a + srpb[ps + j];
    }

    // ---- softmax (duplicated across the quad; identical result) ----
    float mx = s[0];
    #pragma unroll
    for (int j = 1; j < 13; ++j) mx = fmaxf(mx, s[j]);
    float sum = 0.f;
    #pragma unroll
    for (int j = 0; j < 13; ++j) { s[j] = __expf(s[j] - mx); sum += s[j]; }
    const float inv = 1.0f / sum;
    #pragma unroll
    for (int j = 0; j < 13; ++j) s[j] *= inv;

    // ---- weighted sum over the 13 neighbors (16 dims per lane) ----
    float of[16];
    #pragma unroll
    for (int d = 0; d < 16; ++d) of[d] = 0.f;
    #pragma unroll
    for (int j = 0; j < 13; ++j) {
        const uint4* vp = (const uint4*)(vbase + (size_t)(2 * j) * DIMM);
        uint4 u0 = vp[0], u1 = vp[1];
        const float wj = s[j];
        float f[8];
        unpack8(u0, f);
        #pragma unroll
        for (int e = 0; e < 8; ++e) of[e] += wj * f[e];
        unpack8(u1, f);
        #pragma unroll
        for (int e = 0; e < 8; ++e) of[8 + e] += wj * f[e];
    }

    // ---- stage output tile in LDS (f32 [64][66]) for full-line stores ----
    {
        float* orow = &sO[(t >> 2) * 66 + d0];
        #pragma unroll
        for (int c = 0; c < 4; ++c) {
            float4 v4; v4.x = of[c*4+0]; v4.y = of[c*4+1];
            v4.z = of[c*4+2]; v4.w = of[c*4+3];
            *(float4*)&orow[c * 4] = v4;
        }
    }
    __syncthreads();
    {
        const int rr = t >> 4;           // 0..15
        const int cc = (t & 15) * 4;     // 16 lanes x 16B = 256B contiguous/row
        float* Ob = O + bofs;
        #pragma unroll
        for (int r4 = 0; r4 < 4; ++r4) {
            const int r = rr + r4 * 16;
            *(float4*)(Ob + (size_t)(l0 + r) * DIMM + h * DH + cc) =
                *(const float4*)&sO[r * 66 + cc];
        }
    }
}

// ---------------------------------------------------------------------------
extern "C" void kernel_launch(void* const* d_in, const int* in_sizes, int n_in,
                              void* d_out, int out_size, void* d_ws, size_t ws_size,
                              hipStream_t stream) {
    const float* hid = (const float*)d_in[0];
    const float* Wq  = (const float*)d_in[1];
    const float* bq  = (const float*)d_in[2];
    const float* Wk  = (const float*)d_in[3];
    const float* bk  = (const float*)d_in[4];
    const float* Wv  = (const float*)d_in[5];
    const float* bv  = (const float*)d_in[6];
    const float* rpb = (const float*)d_in[7];
    float* out = (float*)d_out;

    ushort_t* ws = (ushort_t*)d_ws;
    ushort_t* Wt = ws;
    const size_t perB = (size_t)LL * DIMM;
    const size_t perF = (size_t)BB * perB;
    const size_t wtEl = (size_t)1536 * 512;
    const size_t need_new = (wtEl + 4 * perF) * sizeof(ushort_t);   // ~270 MB
    const size_t need_bat = (wtEl + 3 * perF) * sizeof(ushort_t);   // ~203 MB

    transpose512<<<dim3(16, 16, 3), dim3(32, 8), 0, stream>>>(Wq, Wk, Wv, Wt);

    if (ws_size >= need_new) {
        ushort_t* Ab = Wt + wtEl;
        ushort_t* Qb = Ab + perF;
        ushort_t* Kb = Qb + perF;
        ushort_t* Vb = Kb + perF;
        conv_bf16<<<2048, 256, 0, stream>>>(hid, Ab);
        qkv_gemm_lds<<<dim3(6144), 256, 0, stream>>>(Ab, Wt, bq, bk, bv, Qb, Kb, Vb);
        na1d_attn<<<dim3(LL / 64, HH, BB), 256, 0, stream>>>(Qb, Kb, Vb, rpb, out);
    } else if (ws_size >= need_bat) {
        ushort_t* Qb = Wt + wtEl;
        ushort_t* Kb = Qb + perF;
        ushort_t* Vb = Kb + perF;
        qkv_gemm<<<dim3(12, 64, BB), 256, 0, stream>>>(hid, Wt, bq, bk, bv, Qb, Kb, Vb);
        na1d_attn<<<dim3(LL / 64, HH, BB), 256, 0, stream>>>(Qb, Kb, Vb, rpb, out);
    } else {
        ushort_t* Qb = Wt + wtEl;
        ushort_t* Kb = Qb + perB;
        ushort_t* Vb = Kb + perB;
        for (int b = 0; b < BB; ++b) {
            const float* hb = hid + (size_t)b * perB;
            float*       ob = out + (size_t)b * perB;
            qkv_gemm<<<dim3(12, 64, 1), 256, 0, stream>>>(hb, Wt, bq, bk, bv, Qb, Kb, Vb);
            na1d_attn<<<dim3(LL / 64, HH, 1), 256, 0, stream>>>(Qb, Kb, Vb, rpb, ob);
        }
    }
}

// Round 6
// 487.225 us; speedup vs baseline: 1.5503x; 1.0141x over previous
//
#include <hip/hip_runtime.h>
#include <stdint.h>

// ---- problem constants ----
#define BB   8
#define LL   8192
#define HH   8
#define DH   64
#define DIMM 512
#define KS_  13
// dilation = 2, ns = 6

typedef unsigned short ushort_t;
typedef __attribute__((ext_vector_type(8))) short bf16x8;   // 8 x bf16 (4 VGPRs)
typedef __attribute__((ext_vector_type(4))) float f32x4;

#define AS1 __attribute__((address_space(1)))
#define AS3 __attribute__((address_space(3)))

__device__ __forceinline__ unsigned short f2bf(float f) {
    unsigned u = __float_as_uint(f);
    u += 0x7fffu + ((u >> 16) & 1u);       // round-to-nearest-even
    return (unsigned short)(u >> 16);
}
__device__ __forceinline__ void unpack8(uint4 u, float* f) {
    f[0] = __uint_as_float(u.x << 16); f[1] = __uint_as_float(u.x & 0xffff0000u);
    f[2] = __uint_as_float(u.y << 16); f[3] = __uint_as_float(u.y & 0xffff0000u);
    f[4] = __uint_as_float(u.z << 16); f[5] = __uint_as_float(u.z & 0xffff0000u);
    f[6] = __uint_as_float(u.w << 16); f[7] = __uint_as_float(u.w & 0xffff0000u);
}
__device__ __forceinline__ uint4 pack8(const float4 a, const float4 b) {
    uint4 u;
    u.x = (unsigned)f2bf(a.x) | ((unsigned)f2bf(a.y) << 16);
    u.y = (unsigned)f2bf(a.z) | ((unsigned)f2bf(a.w) << 16);
    u.z = (unsigned)f2bf(b.x) | ((unsigned)f2bf(b.y) << 16);
    u.w = (unsigned)f2bf(b.z) | ((unsigned)f2bf(b.w) << 16);
    return u;
}

// direct global -> LDS, 16B per lane (global_load_lds_dwordx4).
__device__ __forceinline__ void gload16(const void* g, void* l) {
    __builtin_amdgcn_global_load_lds(
        (const AS1 unsigned int*)(unsigned long long)g,
        (AS3 unsigned int*)(unsigned int)(unsigned long long)l,
        16, 0, 0);
}

// ---------------------------------------------------------------------------
// Kernel 0: convert+transpose the three f32 512x512 weights into bf16
// Wt [1536][512] (n-major: Wt[n][k] = W[k][n])
// ---------------------------------------------------------------------------
__global__ void transpose512(const float* __restrict__ Wq,
                             const float* __restrict__ Wk,
                             const float* __restrict__ Wv,
                             ushort_t* __restrict__ Wt) {
    __shared__ float tile[32][33];
    int mtx = blockIdx.z;
    const float* src = (mtx == 0) ? Wq : ((mtx == 1) ? Wk : Wv);
    ushort_t* dst = Wt + (size_t)mtx * 512 * 512;
    int bx = blockIdx.x * 32, by = blockIdx.y * 32;
    int tx = threadIdx.x, ty = threadIdx.y;
    #pragma unroll
    for (int i = 0; i < 32; i += 8)
        tile[ty + i][tx] = src[(size_t)(by + ty + i) * 512 + bx + tx];
    __syncthreads();
    #pragma unroll
    for (int i = 0; i < 32; i += 8)
        dst[(size_t)(bx + ty + i) * 512 + by + tx] = f2bf(tile[tx][ty + i]);
}

// ---------------------------------------------------------------------------
// Kernel 0b: convert hidden f32 [65536,512] -> bf16 (for global_load_lds GEMM)
// ---------------------------------------------------------------------------
__global__ __launch_bounds__(256) void conv_bf16(const float* __restrict__ in,
                                                 ushort_t* __restrict__ out) {
    const size_t n8 = (size_t)BB * LL * DIMM / 8;
    const size_t stride = (size_t)gridDim.x * 256;
    for (size_t i = (size_t)blockIdx.x * 256 + threadIdx.x; i < n8; i += stride) {
        float4 lo = *((const float4*)in + 2 * i);
        float4 hi = *((const float4*)in + 2 * i + 1);
        *((uint4*)out + i) = pack8(lo, hi);
    }
}

// ---------------------------------------------------------------------------
// Kernel 1: single GEMM  C[65536,1536] = Ab[65536,512] @ Wt^T
// 128x128 tile, 4 waves, 4x4 mfma_16x16x32_bf16, BK=32, global_load_lds.
// v6: 3-buffer, 2-DEEP prefetch with COUNTED vmcnt (T4).  Round-5's 1-deep
// dbuf with drain-to-0 barriers was NULL (161us, MfmaUtil 27%): the barrier
// still drained the just-issued loads (~900cy HBM latency exposed/K-step).
// Now steady state keeps 8 loads in flight; before consuming tile k+1 we
// wait vmcnt(4) (only the loads issued TWO steps ago) + raw s_barrier.
// Wave-local vmcnt + barrier = collective (m201-verified pattern); loads
// retire in issue order.  Tail: vmcnt(0) at kk=14 (only 4 outstanding then,
// vmcnt(4) would pass vacuously).  XCD chunk swizzle kept.
// ---------------------------------------------------------------------------
__global__ __launch_bounds__(256) void qkv_gemm_lds(
    const ushort_t* __restrict__ Ab,   // [65536, 512] bf16
    const ushort_t* __restrict__ Wt,   // [1536, 512] bf16 (W^T, q|k|v)
    const float* __restrict__ bq,
    const float* __restrict__ bk,
    const float* __restrict__ bv,
    ushort_t* __restrict__ Qo,         // [65536, 512] bf16 each
    ushort_t* __restrict__ Ko,
    ushort_t* __restrict__ Vo) {
    __shared__ ushort_t sA[3 * 128 * 32];   // 3 buffers x 8KB = 24KB
    __shared__ ushort_t sB[3 * 128 * 32];

    // XCD swizzle: nwg = 6144 = 8 * 768
    const int bid = blockIdx.x;
    const int lid = (bid & 7) * 768 + (bid >> 3);
    const int tn  = lid % 12;
    const int tm  = lid / 12;
    const int m0  = tm * 128;
    const int ng  = tn * 128;
    const int mtx = ng >> 9;
    const float* bias = (mtx == 0) ? bq : ((mtx == 1) ? bk : bv);
    ushort_t* Co = (mtx == 0) ? Qo : ((mtx == 1) ? Ko : Vo);
    const float scale = (mtx == 0) ? 0.125f : 1.0f;   // 1/sqrt(DH) on q
    const int n0 = ng & 511;

    const int t    = threadIdx.x;
    const int lane = t & 63;
    const int w    = t >> 6;
    const int wm   = w >> 1, wn = w & 1;
    const int md   = lane & 15, qd = lane >> 4;

    f32x4 acc[4][4];
    const f32x4 zero = {0.f, 0.f, 0.f, 0.f};
    #pragma unroll
    for (int i = 0; i < 4; ++i)
        #pragma unroll
        for (int j = 0; j < 4; ++j) acc[i][j] = zero;

    const int sr = t >> 2;
    const int sc = (t & 3) * 8;
    const ushort_t* ga0 = Ab + (size_t)(m0 + sr) * 512 + sc;
    const ushort_t* ga1 = ga0 + (size_t)64 * 512;
    const ushort_t* gb0 = Wt + (size_t)(ng + sr) * 512 + sc;
    const ushort_t* gb1 = gb0 + (size_t)64 * 512;
    const int ld0 = t * 8;             // element offsets within a buffer
    const int ld1 = 2048 + t * 8;

    const int aoff[4] = { (wm * 64 +  0 + md) * 32 + qd * 8,
                          (wm * 64 + 16 + md) * 32 + qd * 8,
                          (wm * 64 + 32 + md) * 32 + qd * 8,
                          (wm * 64 + 48 + md) * 32 + qd * 8 };
    const int boff[4] = { (wn * 64 +  0 + md) * 32 + qd * 8,
                          (wn * 64 + 16 + md) * 32 + qd * 8,
                          (wn * 64 + 32 + md) * 32 + qd * 8,
                          (wn * 64 + 48 + md) * 32 + qd * 8 };

    // prologue: stage tiles 0 and 1 into buffers 0 and 1 (8 loads in flight)
    gload16(ga0,      sA + ld0);
    gload16(ga1,      sA + ld1);
    gload16(gb0,      sB + ld0);
    gload16(gb1,      sB + ld1);
    gload16(ga0 + 32, sA + 4096 + ld0);
    gload16(ga1 + 32, sA + 4096 + ld1);
    gload16(gb0 + 32, sB + 4096 + ld0);
    gload16(gb1 + 32, sB + 4096 + ld1);
    asm volatile("s_waitcnt vmcnt(4)" ::: "memory");   // tile 0 complete
    __builtin_amdgcn_s_barrier();

    for (int kk = 0; kk < 16; ++kk) {
        const int cur = (kk % 3) * 4096;
        if (kk + 2 < 16) {                  // stage tile kk+2 (uniform branch)
            const int nx = ((kk + 2) % 3) * 4096;
            gload16(ga0 + (kk + 2) * 32, sA + nx + ld0);
            gload16(ga1 + (kk + 2) * 32, sA + nx + ld1);
            gload16(gb0 + (kk + 2) * 32, sB + nx + ld0);
            gload16(gb1 + (kk + 2) * 32, sB + nx + ld1);
        }

        bf16x8 af[4], bfv[4];
        #pragma unroll
        for (int mi = 0; mi < 4; ++mi) af[mi]  = *(const bf16x8*)&sA[cur + aoff[mi]];
        #pragma unroll
        for (int ni = 0; ni < 4; ++ni) bfv[ni] = *(const bf16x8*)&sB[cur + boff[ni]];

        #pragma unroll
        for (int mi = 0; mi < 4; ++mi)
            #pragma unroll
            for (int ni = 0; ni < 4; ++ni)
                acc[mi][ni] = __builtin_amdgcn_mfma_f32_16x16x32_bf16(
                    af[mi], bfv[ni], acc[mi][ni], 0, 0, 0);

        // wait for tile kk+1 only (counted), never drain the 2-ahead loads
        if (kk < 14) { asm volatile("s_waitcnt vmcnt(4)" ::: "memory"); }
        else         { asm volatile("s_waitcnt vmcnt(0)" ::: "memory"); }
        __builtin_amdgcn_s_barrier();
    }

    // epilogue: D[row][col], row = qd*4 + r, col = md (verified m89/m91 layout)
    #pragma unroll
    for (int ni = 0; ni < 4; ++ni) {
        const int col = n0 + wn * 64 + ni * 16 + md;
        const float bv_ = bias[col];
        #pragma unroll
        for (int mi = 0; mi < 4; ++mi) {
            const int rbase = m0 + wm * 64 + mi * 16 + qd * 4;
            #pragma unroll
            for (int r = 0; r < 4; ++r) {
                float v = (acc[mi][ni][r] + bv_) * scale;
                Co[(size_t)(rbase + r) * 512 + col] = f2bf(v);
            }
        }
    }
}

// ---------------------------------------------------------------------------
// Kernel 1 (fallback): per-batch register-staged GEMM
// ---------------------------------------------------------------------------
__global__ __launch_bounds__(256) void qkv_gemm(
    const float* __restrict__ A,
    const ushort_t* __restrict__ Wt,
    const float* __restrict__ bq,
    const float* __restrict__ bk,
    const float* __restrict__ bv,
    ushort_t* __restrict__ Qo,
    ushort_t* __restrict__ Ko,
    ushort_t* __restrict__ Vo) {
    __shared__ ushort_t sA[128 * 32];
    __shared__ ushort_t sB[128 * 32];

    const size_t bofs = (size_t)blockIdx.z * LL * DIMM;
    const int t  = threadIdx.x;
    const int m0 = blockIdx.y * 128;
    const int ng = blockIdx.x * 128;
    const int mtx = ng >> 9;
    const float* bias = (mtx == 0) ? bq : ((mtx == 1) ? bk : bv);
    ushort_t* Co = ((mtx == 0) ? Qo : ((mtx == 1) ? Ko : Vo)) + bofs;
    const float scale = (mtx == 0) ? 0.125f : 1.0f;
    const int n0 = ng & 511;

    const int lane = t & 63;
    const int w    = t >> 6;
    const int wm   = w >> 1, wn = w & 1;
    const int md   = lane & 15, qd = lane >> 4;

    f32x4 acc[4][4];
    const f32x4 zero = {0.f, 0.f, 0.f, 0.f};
    #pragma unroll
    for (int i = 0; i < 4; ++i)
        #pragma unroll
        for (int j = 0; j < 4; ++j) acc[i][j] = zero;

    const int ar = t >> 2;
    const int ac = (t & 3) * 8;
    const float*    gA0 = A + bofs + (size_t)(m0 + ar) * 512 + ac;
    const float*    gA1 = gA0 + (size_t)64 * 512;
    const ushort_t* gB0 = Wt + (size_t)(ng + ar) * 512 + ac;
    const ushort_t* gB1 = gB0 + (size_t)64 * 512;
    ushort_t* lA0 = sA + t * 8;
    ushort_t* lA1 = sA + 2048 + t * 8;
    ushort_t* lB0 = sB + t * 8;
    ushort_t* lB1 = sB + 2048 + t * 8;

    const int aoff[4] = { (wm * 64 +  0 + md) * 32 + qd * 8,
                          (wm * 64 + 16 + md) * 32 + qd * 8,
                          (wm * 64 + 32 + md) * 32 + qd * 8,
                          (wm * 64 + 48 + md) * 32 + qd * 8 };
    const int boff[4] = { (wn * 64 +  0 + md) * 32 + qd * 8,
                          (wn * 64 + 16 + md) * 32 + qd * 8,
                          (wn * 64 + 32 + md) * 32 + qd * 8,
                          (wn * 64 + 48 + md) * 32 + qd * 8 };

    for (int kk = 0; kk < 16; ++kk) {
        float4 a0lo = *(const float4*)(gA0 + kk * 32);
        float4 a0hi = *(const float4*)(gA0 + kk * 32 + 4);
        float4 a1lo = *(const float4*)(gA1 + kk * 32);
        float4 a1hi = *(const float4*)(gA1 + kk * 32 + 4);
        uint4 b0 = *(const uint4*)(gB0 + kk * 32);
        uint4 b1 = *(const uint4*)(gB1 + kk * 32);
        uint4 a0 = pack8(a0lo, a0hi);
        uint4 a1 = pack8(a1lo, a1hi);
        __syncthreads();
        *(uint4*)lA0 = a0;
        *(uint4*)lA1 = a1;
        *(uint4*)lB0 = b0;
        *(uint4*)lB1 = b1;
        __syncthreads();

        bf16x8 af[4], bfv[4];
        #pragma unroll
        for (int mi = 0; mi < 4; ++mi) af[mi]  = *(const bf16x8*)&sA[aoff[mi]];
        #pragma unroll
        for (int ni = 0; ni < 4; ++ni) bfv[ni] = *(const bf16x8*)&sB[boff[ni]];

        #pragma unroll
        for (int mi = 0; mi < 4; ++mi)
            #pragma unroll
            for (int ni = 0; ni < 4; ++ni)
                acc[mi][ni] = __builtin_amdgcn_mfma_f32_16x16x32_bf16(
                    af[mi], bfv[ni], acc[mi][ni], 0, 0, 0);
    }

    #pragma unroll
    for (int ni = 0; ni < 4; ++ni) {
        const int col = n0 + wn * 64 + ni * 16 + md;
        const float bv_ = bias[col];
        #pragma unroll
        for (int mi = 0; mi < 4; ++mi) {
            const int rbase = m0 + wm * 64 + mi * 16 + qd * 4;
            #pragma unroll
            for (int r = 0; r < 4; ++r) {
                float v = (acc[mi][ni][r] + bv_) * scale;
                Co[(size_t)(rbase + r) * 512 + col] = f2bf(v);
            }
        }
    }
}

// ---------------------------------------------------------------------------
// Kernel 2: NA1D attention (KS=13, dilation=2), v4 (unchanged from round 5).
// 256 threads/block, lane QUAD per (l,h), 16 dims/lane, 64 l's per block.
// Direct global K/V reads (L1/L2-resident, 13x reuse); LDS output overlay
// for full-line stores.
// ---------------------------------------------------------------------------
__global__ __launch_bounds__(256) void na1d_attn(
    const ushort_t* __restrict__ Q,     // [B][8192, 512] bf16
    const ushort_t* __restrict__ K,
    const ushort_t* __restrict__ V,
    const float* __restrict__ rpb,      // [8][25] f32
    float* __restrict__ O) {            // [B][8192, 512] f32
    __shared__ float sO[64 * 66];       // 16.9 KB output overlay
    __shared__ float srpb[32];

    const int t  = threadIdx.x;
    const int l0 = blockIdx.x * 64;
    const int h  = blockIdx.y;
    const size_t bofs = (size_t)blockIdx.z * LL * DIMM;

    if (t < 25) srpb[t] = rpb[h * 25 + t];

    const int l    = l0 + (t >> 2);
    const int d0   = (t & 3) * 16;      // this lane's 16-dim slice
    const int par  = l & 1;
    const bool lo_e = (l < 12);
    const bool hi_e = (l + 12) >= LL;
    const int ws = lo_e ? par : (hi_e ? (LL - 26 + par) : (l - 12));
    const int ps = lo_e ? (12 - (l >> 1)) : (hi_e ? ((LL - 1 - l) >> 1) : 6);

    const ushort_t* kbase = K + bofs + (size_t)ws * DIMM + h * DH + d0;
    const ushort_t* vbase = V + bofs + (size_t)ws * DIMM + h * DH + d0;

    // ---- q (16 dims) into registers ----
    float qf[16];
    {
        const uint4* qg = (const uint4*)(Q + bofs + (size_t)l * DIMM + h * DH + d0);
        unpack8(qg[0], qf);
        unpack8(qg[1], qf + 8);
    }
    __syncthreads();                    // srpb visible

    // ---- scores: 16-dim partial dot from global (L1/L2-hit), quad combine ----
    float s[13];
    #pragma unroll
    for (int j = 0; j < 13; ++j) {
        const uint4* kp = (const uint4*)(kbase + (size_t)(2 * j) * DIMM);
        uint4 u0 = kp[0], u1 = kp[1];
        float f[8];
        float a = 0.f;
        unpack8(u0, f);
        a += qf[0]*f[0] + qf[1]*f[1] + qf[2]*f[2] + qf[3]*f[3]
           + qf[4]*f[4] + qf[5]*f[5] + qf[6]*f[6] + qf[7]*f[7];
        unpack8(u1, f);
        a += qf[8]*f[0] + qf[9]*f[1] + qf[10]*f[2] + qf[11]*f[3]
           + qf[12]*f[4] + qf[13]*f[5] + qf[14]*f[6] + qf[15]*f[7];
        a += __shfl_xor(a, 1);          // combine the four 16-dim quarters
        a += __shfl_xor(a, 2);
        s[j] = a + srpb[ps + j];
    }

    // ---- softmax (duplicated across the quad; identical result) ----
    float mx = s[0];
    #pragma unroll
    for (int j = 1; j < 13; ++j) mx = fmaxf(mx, s[j]);
    float sum = 0.f;
    #pragma unroll
    for (int j = 0; j < 13; ++j) { s[j] = __expf(s[j] - mx); sum += s[j]; }
    const float inv = 1.0f / sum;
    #pragma unroll
    for (int j = 0; j < 13; ++j) s[j] *= inv;

    // ---- weighted sum over the 13 neighbors (16 dims per lane) ----
    float of[16];
    #pragma unroll
    for (int d = 0; d < 16; ++d) of[d] = 0.f;
    #pragma unroll
    for (int j = 0; j < 13; ++j) {
        const uint4* vp = (const uint4*)(vbase + (size_t)(2 * j) * DIMM);
        uint4 u0 = vp[0], u1 = vp[1];
        const float wj = s[j];
        float f[8];
        unpack8(u0, f);
        #pragma unroll
        for (int e = 0; e < 8; ++e) of[e] += wj * f[e];
        unpack8(u1, f);
        #pragma unroll
        for (int e = 0; e < 8; ++e) of[8 + e] += wj * f[e];
    }

    // ---- stage output tile in LDS (f32 [64][66]) for full-line stores ----
    {
        float* orow = &sO[(t >> 2) * 66 + d0];
        #pragma unroll
        for (int c = 0; c < 4; ++c) {
            float4 v4; v4.x = of[c*4+0]; v4.y = of[c*4+1];
            v4.z = of[c*4+2]; v4.w = of[c*4+3];
            *(float4*)&orow[c * 4] = v4;
        }
    }
    __syncthreads();
    {
        const int rr = t >> 4;           // 0..15
        const int cc = (t & 15) * 4;     // 16 lanes x 16B = 256B contiguous/row
        float* Ob = O + bofs;
        #pragma unroll
        for (int r4 = 0; r4 < 4; ++r4) {
            const int r = rr + r4 * 16;
            *(float4*)(Ob + (size_t)(l0 + r) * DIMM + h * DH + cc) =
                *(const float4*)&sO[r * 66 + cc];
        }
    }
}

// ---------------------------------------------------------------------------
extern "C" void kernel_launch(void* const* d_in, const int* in_sizes, int n_in,
                              void* d_out, int out_size, void* d_ws, size_t ws_size,
                              hipStream_t stream) {
    const float* hid = (const float*)d_in[0];
    const float* Wq  = (const float*)d_in[1];
    const float* bq  = (const float*)d_in[2];
    const float* Wk  = (const float*)d_in[3];
    const float* bk  = (const float*)d_in[4];
    const float* Wv  = (const float*)d_in[5];
    const float* bv  = (const float*)d_in[6];
    const float* rpb = (const float*)d_in[7];
    float* out = (float*)d_out;

    ushort_t* ws = (ushort_t*)d_ws;
    ushort_t* Wt = ws;
    const size_t perB = (size_t)LL * DIMM;
    const size_t perF = (size_t)BB * perB;
    const size_t wtEl = (size_t)1536 * 512;
    const size_t need_new = (wtEl + 4 * perF) * sizeof(ushort_t);   // ~270 MB
    const size_t need_bat = (wtEl + 3 * perF) * sizeof(ushort_t);   // ~203 MB

    transpose512<<<dim3(16, 16, 3), dim3(32, 8), 0, stream>>>(Wq, Wk, Wv, Wt);

    if (ws_size >= need_new) {
        ushort_t* Ab = Wt + wtEl;
        ushort_t* Qb = Ab + perF;
        ushort_t* Kb = Qb + perF;
        ushort_t* Vb = Kb + perF;
        conv_bf16<<<2048, 256, 0, stream>>>(hid, Ab);
        qkv_gemm_lds<<<dim3(6144), 256, 0, stream>>>(Ab, Wt, bq, bk, bv, Qb, Kb, Vb);
        na1d_attn<<<dim3(LL / 64, HH, BB), 256, 0, stream>>>(Qb, Kb, Vb, rpb, out);
    } else if (ws_size >= need_bat) {
        ushort_t* Qb = Wt + wtEl;
        ushort_t* Kb = Qb + perF;
        ushort_t* Vb = Kb + perF;
        qkv_gemm<<<dim3(12, 64, BB), 256, 0, stream>>>(hid, Wt, bq, bk, bv, Qb, Kb, Vb);
        na1d_attn<<<dim3(LL / 64, HH, BB), 256, 0, stream>>>(Qb, Kb, Vb, rpb, out);
    } else {
        ushort_t* Qb = Wt + wtEl;
        ushort_t* Kb = Qb + perB;
        ushort_t* Vb = Kb + perB;
        for (int b = 0; b < BB; ++b) {
            const float* hb = hid + (size_t)b * perB;
            float*       ob = out + (size_t)b * perB;
            qkv_gemm<<<dim3(12, 64, 1), 256, 0, stream>>>(hb, Wt, bq, bk, bv, Qb, Kb, Vb);
            na1d_attn<<<dim3(LL / 64, HH, 1), 256, 0, stream>>>(Qb, Kb, Vb, rpb, ob);
        }
    }
}